// Round 2
// baseline (488.352 us; speedup 1.0000x reference)
//
#include <hip/hip_runtime.h>

#define D_IN 150528
#define FEAT 256
#define HID 64
#define T 4
#define B 8
#define NROWS 1280            // 5 * 256 rows (W1 + 4x dW1)
#define KSPLIT 7
#define TILES_PER_SPLIT 21
#define TILE 1024             // floats per x tile (per batch row)
#define ROWS_PER_BLOCK 16

// ---------------- stage 1: the 5 batched GEMVs over K=150528 ----------------
// grid (KSPLIT, 80), block 256. Each block: 16 rows x 21504 K-slice.
__global__ __launch_bounds__(256) void stage1(
    const float* __restrict__ x, const float* __restrict__ W1,
    const float* __restrict__ dW1, float* __restrict__ partial) {
  __shared__ float xs[B][TILE];                       // 32 KB
  const int ks  = blockIdx.x;                         // 0..6
  const int rg  = blockIdx.y;                         // 0..79
  const int tid = threadIdx.x;
  const int sub  = tid & 15;                          // lane within row
  const int rloc = tid >> 4;                          // 0..15
  const int r = rg * ROWS_PER_BLOCK + rloc;           // 0..1279
  const int m = r >> 8;                               // 0=W1, 1..4=dW1[t]
  const int f = r & 255;
  const float* mrow = (m == 0) ? (W1 + (size_t)f * D_IN)
                               : (dW1 + ((size_t)(m - 1) * FEAT + f) * D_IN);
  const int kbase0 = ks * (TILES_PER_SPLIT * TILE);

  float acc[B];
#pragma unroll
  for (int b = 0; b < B; ++b) acc[b] = 0.f;

  for (int tile = 0; tile < TILES_PER_SPLIT; ++tile) {
    const int kbase = kbase0 + tile * TILE;
    // cooperative load of x[8][TILE] into LDS (2048 float4, 8 per thread)
#pragma unroll
    for (int j = 0; j < 8; ++j) {
      int fi  = j * 256 + tid;                        // float4 index 0..2047
      int b   = fi >> 8;
      int kk4 = fi & 255;
      float4 v = *(const float4*)(x + (size_t)b * D_IN + kbase + kk4 * 4);
      ((float4*)xs[b])[kk4] = v;
    }
    __syncthreads();
#pragma unroll
    for (int j = 0; j < 16; ++j) {
      int kk = sub + j * 16;                          // float4 index in tile
      float4 mv = ((const float4*)(mrow + kbase))[kk];
#pragma unroll
      for (int b = 0; b < B; ++b) {
        float4 xv = ((const float4*)xs[b])[kk];
        acc[b] += mv.x * xv.x + mv.y * xv.y + mv.z * xv.z + mv.w * xv.w;
      }
    }
    __syncthreads();
  }
  // reduce across the 16 lanes of each row-group
#pragma unroll
  for (int b = 0; b < B; ++b) {
    float v = acc[b];
    v += __shfl_xor(v, 1, 16);
    v += __shfl_xor(v, 2, 16);
    v += __shfl_xor(v, 4, 16);
    v += __shfl_xor(v, 8, 16);
    acc[b] = v;
  }
  if (sub == 0) {
    float* dst = partial + ((size_t)ks * NROWS + r) * B;
#pragma unroll
    for (int b = 0; b < B; ++b) dst[b] = acc[b];
  }
}

// ---------------- stage 2: reduce K-splits, add biases ----------------
__global__ __launch_bounds__(256) void stage2(
    const float* __restrict__ partial, const float* __restrict__ b1,
    const float* __restrict__ db1, float* __restrict__ hp) {
  int idx = blockIdx.x * 256 + threadIdx.x;           // 0..10239
  int r = idx >> 3, b = idx & 7;
  int m = r >> 8, f = r & 255;
  float s = (m == 0) ? b1[f] : db1[(m - 1) * FEAT + f];
#pragma unroll
  for (int ks = 0; ks < KSPLIT; ++ks)
    s += partial[((size_t)ks * NROWS + r) * B + b];
  hp[idx] = s;                                        // hp[r][b]
}

// ---------------- stage 3a: h, base, MetaNet coefs, u ----------------
__global__ __launch_bounds__(256) void stage3a(
    const float* __restrict__ hp, const float* __restrict__ W2,
    const float* __restrict__ b2, const float* __restrict__ mW1,
    const float* __restrict__ mb1, const float* __restrict__ mW2,
    const float* __restrict__ mb2, float* __restrict__ h_out,
    float* __restrict__ base_out, float* __restrict__ coef_out,
    float* __restrict__ u_out) {
  __shared__ float h_l[B][FEAT];
  __shared__ float base_l[B][FEAT];
  __shared__ float mid_l[B][HID];
  __shared__ float c_l[B][T];
  const int tid = threadIdx.x;                        // == f (and == g)

  // h = relu(hpre)
  for (int b = 0; b < B; ++b) {
    float v = hp[(size_t)tid * B + b];                // m=0 rows: r == f
    float hv = v > 0.f ? v : 0.f;
    h_l[b][tid] = hv;
    h_out[b * FEAT + tid] = hv;
  }
  __syncthreads();

  // base[b][g] = b2[g] + h[b]·W2[g]
  {
    const float* wrow = W2 + (size_t)tid * FEAT;
    for (int b = 0; b < B; ++b) {
      float s = b2[tid];
      for (int f = 0; f < FEAT; ++f) s += h_l[b][f] * wrow[f];
      base_l[b][tid] = s;
      base_out[b * FEAT + tid] = s;
    }
  }
  __syncthreads();

  // mid[b][hid] = relu(mb1 + base[b]·mW1[hid])
  {
    int b = tid >> 5, h0 = tid & 31;
    for (int hh = h0; hh < HID; hh += 32) {
      float s = mb1[hh];
      const float* wrow = mW1 + hh * FEAT;
      for (int f = 0; f < FEAT; ++f) s += base_l[b][f] * wrow[f];
      mid_l[b][hh] = s > 0.f ? s : 0.f;
    }
  }
  __syncthreads();

  // coefs[b][t]
  if (tid < B * T) {
    int b = tid >> 2, t = tid & 3;
    float s = mb2[t];
    const float* wrow = mW2 + t * HID;
    for (int hh = 0; hh < HID; ++hh) s += mid_l[b][hh] * wrow[hh];
    c_l[b][t] = s;
    coef_out[tid] = s;
  }
  __syncthreads();

  // u[b][f] = (hpre>0) * sum_t c[b,t]*dhpre[t,b,f]
  for (int b = 0; b < B; ++b) {
    float hpre = hp[(size_t)tid * B + b];
    float s = 0.f;
    if (hpre > 0.f) {
#pragma unroll
      for (int t = 0; t < T; ++t)
        s += c_l[b][t] * hp[((size_t)(1 + t) * FEAT + tid) * B + b];
    }
    u_out[b * FEAT + tid] = s;
  }
}

// ---------------- stage 3b: final combine ----------------
__global__ __launch_bounds__(256) void stage3b(
    const float* __restrict__ h, const float* __restrict__ base,
    const float* __restrict__ coef, const float* __restrict__ u,
    const float* __restrict__ W2, const float* __restrict__ dW2,
    const float* __restrict__ db2, float* __restrict__ out) {
  __shared__ float h_l[FEAT];
  __shared__ float u_l[FEAT];
  const int b = blockIdx.x;
  const int g = threadIdx.x;
  h_l[g] = h[b * FEAT + g];
  u_l[g] = u[b * FEAT + g];
  __syncthreads();
  float c[T];
#pragma unroll
  for (int t = 0; t < T; ++t) c[t] = coef[b * T + t];
  float s = base[b * FEAT + g];
#pragma unroll
  for (int t = 0; t < T; ++t) s += c[t] * db2[t * FEAT + g];
  const float* wrow = W2 + (size_t)g * FEAT;
  float acc1 = 0.f;
  float acc2[T] = {0.f, 0.f, 0.f, 0.f};
  for (int f = 0; f < FEAT; ++f) {
    acc1 += u_l[f] * wrow[f];
#pragma unroll
    for (int t = 0; t < T; ++t)
      acc2[t] += h_l[f] * dW2[(((size_t)t * FEAT) + g) * FEAT + f];
  }
  s += acc1;
#pragma unroll
  for (int t = 0; t < T; ++t) s += c[t] * acc2[t];
  out[b * FEAT + g] = s;
}

extern "C" void kernel_launch(void* const* d_in, const int* in_sizes, int n_in,
                              void* d_out, int out_size, void* d_ws, size_t ws_size,
                              hipStream_t stream) {
  const float* x   = (const float*)d_in[0];
  const float* W1  = (const float*)d_in[1];
  const float* b1  = (const float*)d_in[2];
  const float* W2  = (const float*)d_in[3];
  const float* b2  = (const float*)d_in[4];
  const float* mW1 = (const float*)d_in[5];
  const float* mb1 = (const float*)d_in[6];
  const float* mW2 = (const float*)d_in[7];
  const float* mb2 = (const float*)d_in[8];
  const float* dW1 = (const float*)d_in[9];
  const float* db1 = (const float*)d_in[10];
  const float* dW2 = (const float*)d_in[11];
  const float* db2 = (const float*)d_in[12];
  float* out = (float*)d_out;

  float* ws   = (float*)d_ws;
  float* P    = ws;               // [7][1280][8]   = 71680 floats
  float* HP   = P + 71680;        // [1280][8]      = 10240
  float* H    = HP + 10240;       // [8][256]       = 2048
  float* BASE = H + 2048;         // [8][256]       = 2048
  float* U    = BASE + 2048;      // [8][256]       = 2048
  float* C    = U + 2048;         // [8][4]         = 32

  stage1<<<dim3(KSPLIT, 80), 256, 0, stream>>>(x, W1, dW1, P);
  stage2<<<40, 256, 0, stream>>>(P, b1, db1, HP);
  stage3a<<<1, 256, 0, stream>>>(HP, W2, b2, mW1, mb1, mW2, mb2, H, BASE, C, U);
  stage3b<<<B, 256, 0, stream>>>(H, BASE, C, U, W2, dW2, db2, out);
}

// Round 3
// 302.381 us; speedup vs baseline: 1.6150x; 1.6150x over previous
//
#include <hip/hip_runtime.h>

#define D_IN 150528
#define FEAT 256
#define HID 64
#define T 4
#define B 8
#define NROWS 1280            // 5 * 256 rows (W1 + 4x dW1)
#define TILE 1024             // floats per x tile (per batch row)
#define RPT 4                 // rows per thread
#define ROWS_PER_BLOCK 64     // 16 groups x RPT
#define NRB 20                // 1280 / 64

// ---------------- stage 1: the 5 batched GEMVs over K=150528 ----------------
// grid (ksplit, 20), block 256. Block: 64 rows x (tiles*1024) K-slice.
// Each thread: 4 rows x 8 batch -> each LDS x-read feeds 16 FMAs.
__global__ __launch_bounds__(256) void stage1(
    const float* __restrict__ x, const float* __restrict__ W1,
    const float* __restrict__ dW1, float* __restrict__ partial, int tiles) {
  __shared__ float xs[B][TILE];                       // 32 KB
  const int ks  = blockIdx.x;
  const int rg  = blockIdx.y;                         // 0..19
  const int tid = threadIdx.x;
  const int sub  = tid & 15;                          // lane within row-group
  const int rloc = tid >> 4;                          // 0..15
  const int r0 = rg * ROWS_PER_BLOCK + rloc * RPT;    // 4 consecutive rows
  const float* rowp[RPT];
#pragma unroll
  for (int i = 0; i < RPT; ++i) {
    int r = r0 + i, m = r >> 8, f = r & 255;
    rowp[i] = (m == 0) ? (W1 + (size_t)f * D_IN)
                       : (dW1 + ((size_t)(m - 1) * FEAT + f) * D_IN);
  }
  const int kbase0 = ks * tiles * TILE;

  float acc[RPT][B];
#pragma unroll
  for (int i = 0; i < RPT; ++i)
#pragma unroll
    for (int b = 0; b < B; ++b) acc[i][b] = 0.f;

  for (int t = 0; t < tiles; ++t) {
    const int kbase = kbase0 + t * TILE;
    // cooperative load of x[8][TILE] into LDS (2048 float4, 8 per thread)
#pragma unroll
    for (int j = 0; j < 8; ++j) {
      int fi  = j * 256 + tid;                        // float4 index 0..2047
      int b   = fi >> 8;
      int k4  = fi & 255;
      ((float4*)xs[b])[k4] =
          *(const float4*)(x + (size_t)b * D_IN + kbase + k4 * 4);
    }
    __syncthreads();
#pragma unroll 4
    for (int j = 0; j < 16; ++j) {
      const int kk = sub + j * 16;                    // float4 index in tile
      float4 mv[RPT];
#pragma unroll
      for (int i = 0; i < RPT; ++i)
        mv[i] = ((const float4*)(rowp[i] + kbase))[kk];
#pragma unroll
      for (int b = 0; b < B; ++b) {
        float4 xv = ((const float4*)xs[b])[kk];
#pragma unroll
        for (int i = 0; i < RPT; ++i)
          acc[i][b] += mv[i].x * xv.x + mv[i].y * xv.y +
                       mv[i].z * xv.z + mv[i].w * xv.w;
      }
    }
    __syncthreads();
  }
  // reduce across the 16 lanes of each row-group
#pragma unroll
  for (int i = 0; i < RPT; ++i)
#pragma unroll
    for (int b = 0; b < B; ++b) {
      float v = acc[i][b];
      v += __shfl_xor(v, 1, 16);
      v += __shfl_xor(v, 2, 16);
      v += __shfl_xor(v, 4, 16);
      v += __shfl_xor(v, 8, 16);
      acc[i][b] = v;
    }
  if (sub == 0) {
#pragma unroll
    for (int i = 0; i < RPT; ++i) {
      float* dst = partial + ((size_t)ks * NROWS + r0 + i) * B;
#pragma unroll
      for (int b = 0; b < B; ++b) dst[b] = acc[i][b];
    }
  }
}

// ---------------- stage 2: reduce K-splits, add biases ----------------
__global__ __launch_bounds__(256) void stage2(
    const float* __restrict__ partial, const float* __restrict__ b1,
    const float* __restrict__ db1, float* __restrict__ hp, int ksplit) {
  int idx = blockIdx.x * 256 + threadIdx.x;           // 0..10239
  int r = idx >> 3, b = idx & 7;
  int m = r >> 8, f = r & 255;
  float s = (m == 0) ? b1[f] : db1[(m - 1) * FEAT + f];
  for (int ks = 0; ks < ksplit; ++ks)
    s += partial[((size_t)ks * NROWS + r) * B + b];
  hp[idx] = s;                                        // hp[r][b]
}

// ---------------- stage 3a: h, base, MetaNet coefs, u ----------------
__global__ __launch_bounds__(256) void stage3a(
    const float* __restrict__ hp, const float* __restrict__ W2,
    const float* __restrict__ b2, const float* __restrict__ mW1,
    const float* __restrict__ mb1, const float* __restrict__ mW2,
    const float* __restrict__ mb2, float* __restrict__ h_out,
    float* __restrict__ base_out, float* __restrict__ coef_out,
    float* __restrict__ u_out) {
  __shared__ float h_l[B][FEAT];
  __shared__ float base_l[B][FEAT];
  __shared__ float mid_l[B][HID];
  __shared__ float c_l[B][T];
  const int tid = threadIdx.x;                        // == f (and == g)

  // h = relu(hpre)
  for (int b = 0; b < B; ++b) {
    float v = hp[(size_t)tid * B + b];                // m=0 rows: r == f
    float hv = v > 0.f ? v : 0.f;
    h_l[b][tid] = hv;
    h_out[b * FEAT + tid] = hv;
  }
  __syncthreads();

  // base[b][g] = b2[g] + h[b]·W2[g]
  {
    const float* wrow = W2 + (size_t)tid * FEAT;
    for (int b = 0; b < B; ++b) {
      float s = b2[tid];
      for (int f = 0; f < FEAT; ++f) s += h_l[b][f] * wrow[f];
      base_l[b][tid] = s;
      base_out[b * FEAT + tid] = s;
    }
  }
  __syncthreads();

  // mid[b][hid] = relu(mb1 + base[b]·mW1[hid])
  {
    int b = tid >> 5, h0 = tid & 31;
    for (int hh = h0; hh < HID; hh += 32) {
      float s = mb1[hh];
      const float* wrow = mW1 + hh * FEAT;
      for (int f = 0; f < FEAT; ++f) s += base_l[b][f] * wrow[f];
      mid_l[b][hh] = s > 0.f ? s : 0.f;
    }
  }
  __syncthreads();

  // coefs[b][t]
  if (tid < B * T) {
    int b = tid >> 2, t = tid & 3;
    float s = mb2[t];
    const float* wrow = mW2 + t * HID;
    for (int hh = 0; hh < HID; ++hh) s += mid_l[b][hh] * wrow[hh];
    c_l[b][t] = s;
    coef_out[tid] = s;
  }
  __syncthreads();

  // u[b][f] = (hpre>0) * sum_t c[b,t]*dhpre[t,b,f]
  for (int b = 0; b < B; ++b) {
    float hpre = hp[(size_t)tid * B + b];
    float s = 0.f;
    if (hpre > 0.f) {
#pragma unroll
      for (int t = 0; t < T; ++t)
        s += c_l[b][t] * hp[((size_t)(1 + t) * FEAT + tid) * B + b];
    }
    u_out[b * FEAT + tid] = s;
  }
}

// ---------------- stage 3b: final combine ----------------
__global__ __launch_bounds__(256) void stage3b(
    const float* __restrict__ h, const float* __restrict__ base,
    const float* __restrict__ coef, const float* __restrict__ u,
    const float* __restrict__ W2, const float* __restrict__ dW2,
    const float* __restrict__ db2, float* __restrict__ out) {
  __shared__ float h_l[FEAT];
  __shared__ float u_l[FEAT];
  const int b = blockIdx.x;
  const int g = threadIdx.x;
  h_l[g] = h[b * FEAT + g];
  u_l[g] = u[b * FEAT + g];
  __syncthreads();
  float c[T];
#pragma unroll
  for (int t = 0; t < T; ++t) c[t] = coef[b * T + t];
  float s = base[b * FEAT + g];
#pragma unroll
  for (int t = 0; t < T; ++t) s += c[t] * db2[t * FEAT + g];
  const float* wrow = W2 + (size_t)g * FEAT;
  float acc1 = 0.f;
  float acc2[T] = {0.f, 0.f, 0.f, 0.f};
  for (int f = 0; f < FEAT; ++f) {
    acc1 += u_l[f] * wrow[f];
#pragma unroll
    for (int t = 0; t < T; ++t)
      acc2[t] += h_l[f] * dW2[(((size_t)t * FEAT) + g) * FEAT + f];
  }
  s += acc1;
#pragma unroll
  for (int t = 0; t < T; ++t) s += c[t] * acc2[t];
  out[b * FEAT + g] = s;
}

extern "C" void kernel_launch(void* const* d_in, const int* in_sizes, int n_in,
                              void* d_out, int out_size, void* d_ws, size_t ws_size,
                              hipStream_t stream) {
  const float* x   = (const float*)d_in[0];
  const float* W1  = (const float*)d_in[1];
  const float* b1  = (const float*)d_in[2];
  const float* W2  = (const float*)d_in[3];
  const float* b2  = (const float*)d_in[4];
  const float* mW1 = (const float*)d_in[5];
  const float* mb1 = (const float*)d_in[6];
  const float* mW2 = (const float*)d_in[7];
  const float* mb2 = (const float*)d_in[8];
  const float* dW1 = (const float*)d_in[9];
  const float* db1 = (const float*)d_in[10];
  const float* dW2 = (const float*)d_in[11];
  const float* db2 = (const float*)d_in[12];
  float* out = (float*)d_out;

  // 147 K-tiles of 1024; pick the largest split whose partials fit d_ws.
  int ksplit = 49, tiles = 3;                         // preferred: 980 blocks
  {
    const int opts_ks[3]   = {49, 21, 7};
    const int opts_tile[3] = {3, 7, 21};
    for (int o = 0; o < 3; ++o) {
      size_t need = ((size_t)opts_ks[o] * NROWS * B + 10240 + 3 * 2048 + 32)
                    * sizeof(float);
      if (need <= ws_size) { ksplit = opts_ks[o]; tiles = opts_tile[o]; break; }
    }
  }

  float* ws   = (float*)d_ws;
  float* P    = ws;                              // [ksplit][1280][8]
  float* HP   = P + (size_t)ksplit * NROWS * B;  // [1280][8] = 10240
  float* H    = HP + 10240;                      // [8][256]
  float* BASE = H + 2048;                        // [8][256]
  float* U    = BASE + 2048;                     // [8][256]
  float* C    = U + 2048;                        // [8][4]

  stage1<<<dim3(ksplit, NRB), 256, 0, stream>>>(x, W1, dW1, P, tiles);
  stage2<<<40, 256, 0, stream>>>(P, b1, db1, HP, ksplit);
  stage3a<<<1, 256, 0, stream>>>(HP, W2, b2, mW1, mb1, mW2, mb2, H, BASE, C, U);
  stage3b<<<B, 256, 0, stream>>>(H, BASE, C, U, W2, dW2, db2, out);
}